// Round 13
// baseline (713.641 us; speedup 1.0000x reference)
//
#include <hip/hip_runtime.h>
#include <math.h>

// ---------------- dims ----------------
constexpr int NP_ = 272;               // padded tokens per batch (17 tiles of 16)
constexpr int MP_ = 64 * NP_;          // 17408 padded rows
constexpr int TPB_ = 17;               // tiles per batch

typedef short short8 __attribute__((ext_vector_type(8)));
typedef float f32x4 __attribute__((ext_vector_type(4)));

__device__ inline short f2bs(float f) {  // float -> bf16 bits, RNE
    unsigned u = __builtin_bit_cast(unsigned, f);
    unsigned r = (u + 0x7fffu + ((u >> 16) & 1u)) >> 16;
    return (short)r;
}

__device__ inline unsigned f2bs2(float a, float b) {  // packed bf16 pair
    unsigned ua = __builtin_bit_cast(unsigned, a);
    unsigned ub = __builtin_bit_cast(unsigned, b);
    unsigned ra = (ua + 0x7fffu + ((ua >> 16) & 1u)) >> 16;
    unsigned rb = (ub + 0x7fffu + ((ub >> 16) & 1u)) & 0xffff0000u;
    return ra | rb;
}

__device__ inline f32x4 mfma16(short8 a, short8 b, f32x4 c) {
    return __builtin_amdgcn_mfma_f32_16x16x32_bf16(a, b, c, 0, 0, 0);
}

// ---------------- one-shot weight repack (vectorized: 8 elems/thread for matrices) ----------------
__global__ void repack_all(const float* __restrict__ qkvw, const float* __restrict__ projw,
                           const float* __restrict__ f1w, const float* __restrict__ f2w,
                           const float* __restrict__ convw,
                           short* __restrict__ wq, short* __restrict__ wp,
                           short* __restrict__ w1, short* __restrict__ w2,
                           short* __restrict__ wc) {
    int t = blockIdx.x * 256 + threadIdx.x;            // grid covers 589824 tasks
    if (t < 294912) {                                  // vec task: 8 consecutive outputs
        int o = t * 8;
        const float* src;
        short* dst;
        int Nn, K, per;
        if (o < 589824) { src = qkvw; dst = wq; Nn = 384; K = 128; per = 49152; }
        else if (o < 786432) { o -= 589824; src = projw; dst = wp; Nn = 128; K = 128; per = 16384; }
        else if (o < 1572864) { o -= 786432; src = f1w; dst = w1; Nn = 512; K = 128; per = 65536; }
        else { o -= 1572864; src = f2w; dst = w2; Nn = 128; K = 512; per = 65536; }
        int l = o / per, r = o % per;
        int chunk = r / (Nn * 8), w = r % (Nn * 8);
        int n = w >> 3;
        const float* ip = src + (size_t)l * per + (size_t)n * K + chunk * 8;
        float4 a = *(const float4*)ip;
        float4 b = *(const float4*)(ip + 4);
        uint4 ov;
        ov.x = f2bs2(a.x, a.y);
        ov.y = f2bs2(a.z, a.w);
        ov.z = f2bs2(b.x, b.y);
        ov.w = f2bs2(b.z, b.w);
        *(uint4*)(dst + o) = ov;
        return;
    }
    int o = t - 294912;                                // conv scalar task
    if (o < 294912) {
        int j = o & 7;
        int col = (o >> 3) & 127;
        int c = o >> 10;
        int qd = c & 3, cscb = c >> 2;
        int cs = cscb & 7, kykx = cscb >> 3;
        int cin = cs * 32 + qd * 8 + j;
        int ky = kykx / 3, kx = kykx % 3;
        wc[o] = f2bs(convw[((col * 256 + cin) * 3 + ky) * 3 + kx]);
    }
}

// conv as GEMM: block = (batch-pair, oy). Weights reused across 2 batches (L2 traffic halved).
// Per ky: stage both batches' input row (one row at a time through tmp), then MFMA both.
__global__ __launch_bounds__(256, 3) void conv_gemm(const float* __restrict__ feat, const short* __restrict__ wr,
                                                    const float* __restrict__ cb, const float* __restrict__ pos,
                                                    const float* __restrict__ cls, float* __restrict__ X) {
    __shared__ __align__(16) short Ain[2][34 * 256];   // 34.8 KB (one row per batch)
    __shared__ float tmp[64 * 33];                     // 8.4 KB
    int bp = blockIdx.x >> 4, oy = blockIdx.x & 15;
    int b0 = bp * 2;
    int tid = threadIdx.x;
    for (int idx = tid; idx < 1024; idx += 256) {      // zero px=0/33 columns, both buffers
        int c = idx & 255;
        int px = ((idx >> 8) & 1) ? 33 : 0;
        int bi = idx >> 9;
        Ain[bi][px * 256 + c] = 0;
    }
    int wave = tid >> 6, lane = tid & 63;
    int ng = wave, lo = lane & 15, qd = lane >> 4;
    // slice g (0..23): ky=g>>3, bi=(g>>2)&1, s=g&3
    auto load_slice = [&](int g, float4& A, float4& B) {
        int ky = g >> 3, bi = (g >> 2) & 1, s = g & 3;
        int cbase = s * 64;
        int y = 2 * oy + ky - 1;
        int b = b0 + bi;
        A = make_float4(0.f, 0.f, 0.f, 0.f);
        B = A;
        if (y >= 0 && y < 32) {
            int cl = tid >> 3, x4 = tid & 7;
            A = *(const float4*)(feat + (((size_t)(b * 256 + cbase + cl) * 32 + y) * 32 + x4 * 4));
            int i2 = tid + 256;
            int cl2 = i2 >> 3, x42 = i2 & 7;
            B = *(const float4*)(feat + (((size_t)(b * 256 + cbase + cl2) * 32 + y) * 32 + x42 * 4));
        }
    };
    f32x4 acc[2][2] = {};
    float4 ra, rb;
    load_slice(0, ra, rb);
    for (int ky = 0; ky < 3; ++ky) {
        for (int t8 = 0; t8 < 8; ++t8) {
            int g = ky * 8 + t8;
            int bi = (g >> 2) & 1, s = g & 3;
            {   // regs -> tmp (conflict-free)
                int cl = tid >> 3, x4 = tid & 7;
                tmp[cl * 33 + x4 * 4 + 0] = ra.x;
                tmp[cl * 33 + x4 * 4 + 1] = ra.y;
                tmp[cl * 33 + x4 * 4 + 2] = ra.z;
                tmp[cl * 33 + x4 * 4 + 3] = ra.w;
                int i2 = tid + 256;
                int cl2 = i2 >> 3, x42 = i2 & 7;
                tmp[cl2 * 33 + x42 * 4 + 0] = rb.x;
                tmp[cl2 * 33 + x42 * 4 + 1] = rb.y;
                tmp[cl2 * 33 + x42 * 4 + 2] = rb.z;
                tmp[cl2 * 33 + x42 * 4 + 3] = rb.w;
            }
            __syncthreads();
            float4 na, nb;
            if (g < 23) load_slice(g + 1, na, nb);
            {   // transposed read -> one vec8 bf16 write into swizzled Ain[bi]
                int px = 1 + (tid & 31), g2 = tid >> 5;
                int sw = (px >> 1) & 7;
                int cg = s * 8 + g2;
                float f[8];
#pragma unroll
                for (int j = 0; j < 8; ++j) f[j] = tmp[(g2 * 8 + j) * 33 + (px - 1)];
                uint4 ov;
                ov.x = f2bs2(f[0], f[1]);
                ov.y = f2bs2(f[2], f[3]);
                ov.z = f2bs2(f[4], f[5]);
                ov.w = f2bs2(f[6], f[7]);
                *(uint4*)(Ain[bi] + px * 256 + ((cg ^ sw) * 8)) = ov;
            }
            __syncthreads();
            ra = na;
            rb = nb;
        }
        // MFMA over this ky row for both batches (weights loaded once, used 4x)
#pragma unroll
        for (int kx = 0; kx < 3; ++kx) {
            int sx = 2 * lo + kx;
            int arow = sx * 256;
            int sw = (sx >> 1) & 7;
            const short* wb = wr + (((size_t)((ky * 3 + kx) * 8) * 4 + qd) * 128 + ng * 32 + lo) * 8;
#pragma unroll
            for (int cs = 0; cs < 8; ++cs) {
                int aoff = arow + (((cs * 4 + qd) ^ sw) * 8);
                short8 af0 = *(const short8*)(Ain[0] + aoff);
                short8 af1 = *(const short8*)(Ain[1] + aoff);
                short8 w0 = *(const short8*)(wb + (size_t)cs * 4096);
                short8 w1v = *(const short8*)(wb + (size_t)cs * 4096 + 128);
                acc[0][0] = mfma16(af0, w0, acc[0][0]);
                acc[0][1] = mfma16(af0, w1v, acc[0][1]);
                acc[1][0] = mfma16(af1, w0, acc[1][0]);
                acc[1][1] = mfma16(af1, w1v, acc[1][1]);
            }
        }
    }
#pragma unroll
    for (int bi = 0; bi < 2; ++bi) {
        int b = b0 + bi;
#pragma unroll
        for (int t = 0; t < 2; ++t) {
            int e = ng * 32 + t * 16 + lo;
            float bias = cb[e];
#pragma unroll
            for (int r = 0; r < 4; ++r) {
                int tok = 1 + oy * 16 + qd * 4 + r;
                X[((size_t)b * NP_ + tok) * 128 + e] = acc[bi][t][r] + bias + pos[tok * 128 + e];
            }
        }
    }
    if (oy == 0) {                                     // cls token + pad rows, both batches
#pragma unroll
        for (int bi = 0; bi < 2; ++bi) {
            int b = b0 + bi;
            if (tid < 128) X[(size_t)b * NP_ * 128 + tid] = cls[tid] + pos[tid];
            for (int idx = tid; idx < 15 * 128; idx += 256)
                X[((size_t)b * NP_ + 257) * 128 + idx] = 0.f;
        }
    }
}

// LN of a 16-row slab of Xl (stride 132) -> A-frag tile SB[kq(16)][m(16)][8]. 256 threads.
__device__ inline void ln_tile16(const float* Xl, const float* __restrict__ s, const float* __restrict__ bb,
                                 short* SB, int tid, float eps) {
    int wv = tid >> 6, lane = tid & 63;
    int r4 = lane & 3, c32 = lane >> 2;
    int row = wv * 4 + r4;
    const float* xr = Xl + row * 132 + c32 * 8;
    float4 a = *(const float4*)(xr);
    float4 b = *(const float4*)(xr + 4);
    float v[8] = {a.x, a.y, a.z, a.w, b.x, b.y, b.z, b.w};
    float sum = v[0] + v[1] + v[2] + v[3] + v[4] + v[5] + v[6] + v[7];
    sum += __shfl_xor(sum, 4); sum += __shfl_xor(sum, 8);
    sum += __shfl_xor(sum, 16); sum += __shfl_xor(sum, 32);
    float mean = sum * (1.f / 128.f);
    float vs = 0.f;
#pragma unroll
    for (int j = 0; j < 8; ++j) { float d = v[j] - mean; vs += d * d; }
    vs += __shfl_xor(vs, 4); vs += __shfl_xor(vs, 8);
    vs += __shfl_xor(vs, 16); vs += __shfl_xor(vs, 32);
    float rs = rsqrtf(vs * (1.f / 128.f) + eps);
    float4 s0 = *(const float4*)(s + c32 * 8), s1 = *(const float4*)(s + c32 * 8 + 4);
    float4 b0 = *(const float4*)(bb + c32 * 8), b1 = *(const float4*)(bb + c32 * 8 + 4);
    float sv[8] = {s0.x, s0.y, s0.z, s0.w, s1.x, s1.y, s1.z, s1.w};
    float bv[8] = {b0.x, b0.y, b0.z, b0.w, b1.x, b1.y, b1.z, b1.w};
    float y[8];
#pragma unroll
    for (int j = 0; j < 8; ++j) y[j] = (v[j] - mean) * rs * sv[j] + bv[j];
    uint4 ov;
    ov.x = f2bs2(y[0], y[1]);
    ov.y = f2bs2(y[2], y[3]);
    ov.z = f2bs2(y[4], y[5]);
    ov.w = f2bs2(y[6], y[7]);
    *(uint4*)(SB + (c32 * 16 + row) * 8) = ov;
}

// qkv GEMM from SB frags (2 m-tiles); ki=0 B-frags prefetched; Q pre-scaled; V packed 8B stores.
__device__ inline void qkv_stage32(const short* SB, const short* __restrict__ wq, const float* __restrict__ qb,
                                   const short8* pre, int mg, int wv, int lo, int qd,
                                   short* __restrict__ Qf, short* __restrict__ Kf, short* __restrict__ Vt) {
    int n0 = wv * 96;
    f32x4 acc[2][6] = {};
#pragma unroll
    for (int ki = 0; ki < 4; ++ki) {
        int kq = ki * 4 + qd;
        short8 a0 = *(const short8*)(SB + (kq * 16 + lo) * 8);
        short8 a1 = *(const short8*)(SB + 2048 + (kq * 16 + lo) * 8);
#pragma unroll
        for (int t = 0; t < 6; ++t) {
            short8 bf = (ki == 0) ? pre[t]
                                  : *(const short8*)(wq + ((size_t)kq * 384 + n0 + t * 16 + lo) * 8);
            acc[0][t] = mfma16(a0, bf, acc[0][t]);
            acc[1][t] = mfma16(a1, bf, acc[1][t]);
        }
    }
#pragma unroll
    for (int mt = 0; mt < 2; ++mt)
#pragma unroll
        for (int t = 0; t < 6; ++t) {
            int n = n0 + t * 16 + lo;
            float bvv = qb[n];
            int seg = n >> 7, m = n & 127, h = m >> 5, d = m & 31;
            int row0 = mg * 32 + mt * 16 + qd * 4;
            int bb2 = row0 / NP_, q0 = row0 - bb2 * NP_;
            if (seg == 2) {
                uint2 u;
                u.x = f2bs2(acc[mt][t][0] + bvv, acc[mt][t][1] + bvv);
                u.y = f2bs2(acc[mt][t][2] + bvv, acc[mt][t][3] + bvv);
                *(uint2*)(Vt + ((size_t)(bb2 * 4 + h) * 32 + d) * NP_ + q0) = u;
            } else {
                float qs = (seg == 0) ? 0.17677669529663687f : 1.f;  // fold softmax scale into Q
#pragma unroll
                for (int r = 0; r < 4; ++r) {
                    short val = f2bs((acc[mt][t][r] + bvv) * qs);
                    (seg ? Kf : Qf)[((size_t)(bb2 * 4 + h) * 4 + (d >> 3)) * (NP_ * 8) + (q0 + r) * 8 + (d & 7)] = val;
                }
            }
        }
}

// layer-0 qkv: LN1(X) -> frags -> qkv  (32 tokens/block)
__global__ __launch_bounds__(256, 3) void qkv0(const float* __restrict__ X, const short* __restrict__ wq,
                                               const float* __restrict__ qb, const float* __restrict__ ls,
                                               const float* __restrict__ lb,
                                               short* __restrict__ Qf, short* __restrict__ Kf,
                                               short* __restrict__ Vt) {
    __shared__ __align__(16) float Xl[32 * 132];
    __shared__ __align__(16) short SB[2 * 2048];
    int mg = blockIdx.x, tid = threadIdx.x;
    int wv = tid >> 6, lane = tid & 63, lo = lane & 15, qd = lane >> 4;
    for (int idx = tid; idx < 1024; idx += 256) {
        int tok = idx >> 5, c = idx & 31;
        *(float4*)(Xl + tok * 132 + c * 4) = *(const float4*)(X + (size_t)(mg * 32 + tok) * 128 + c * 4);
    }
    short8 preq[6];
#pragma unroll
    for (int t = 0; t < 6; ++t)
        preq[t] = *(const short8*)(wq + ((size_t)qd * 384 + wv * 96 + t * 16 + lo) * 8);
    __syncthreads();
    ln_tile16(Xl, ls, lb, SB, tid, 1e-5f);
    ln_tile16(Xl + 16 * 132, ls, lb, SB + 2048, tid, 1e-5f);
    __syncthreads();
    qkv_stage32(SB, wq, qb, preq, mg, wv, lo, qd, Qf, Kf, Vt);
}

// Fused layer tail, 32 tokens/block (2 m-tiles), stage-entry weights prefetched.
template <int LAST>
__global__ __launch_bounds__(256, 3) void layer_tail(
    const short* __restrict__ Of, const short* __restrict__ wp, const float* __restrict__ pb,
    const float* __restrict__ l2s, const float* __restrict__ l2b,
    const short* __restrict__ w1, const float* __restrict__ b1,
    const short* __restrict__ w2, const float* __restrict__ b2,
    float* __restrict__ X,
    const float* __restrict__ l1s, const float* __restrict__ l1b,
    const short* __restrict__ wq, const float* __restrict__ qb,
    short* __restrict__ Qf, short* __restrict__ Kf, short* __restrict__ Vt) {
    __shared__ __align__(16) short SB[2 * 2048];       // 8 KB
    __shared__ __align__(16) float Xl[32 * 132];       // 16.9 KB
    __shared__ __align__(16) short Uh[2 * 32 * 136];   // 17.4 KB
    int mg = blockIdx.x, tid = threadIdx.x;
    int wv = tid >> 6, lane = tid & 63, lo = lane & 15, qd = lane >> 4;
    const short* osrc = Of + (size_t)mg * 4096;
    for (int idx = tid; idx < 512; idx += 256)
        *(short8*)(SB + idx * 8) = *(const short8*)(osrc + idx * 8);
    for (int idx = tid; idx < 1024; idx += 256) {
        int tok = idx >> 5, c = idx & 31;
        *(float4*)(Xl + tok * 132 + c * 4) = *(const float4*)(X + (size_t)(mg * 32 + tok) * 128 + c * 4);
    }
    int n0 = wv * 32;
    short8 prep[8];
#pragma unroll
    for (int ki = 0; ki < 4; ++ki) {
        int kq = ki * 4 + qd;
        prep[ki * 2] = *(const short8*)(wp + ((size_t)kq * 128 + n0 + lo) * 8);
        prep[ki * 2 + 1] = *(const short8*)(wp + ((size_t)kq * 128 + n0 + 16 + lo) * 8);
    }
    __syncthreads();
    // ---- proj: wave owns 32 cols, 2 m-tiles ----
    {
        f32x4 pa[2][2] = {};
#pragma unroll
        for (int ki = 0; ki < 4; ++ki) {
            int kq = ki * 4 + qd;
            short8 a0 = *(const short8*)(SB + (kq * 16 + lo) * 8);
            short8 a1 = *(const short8*)(SB + 2048 + (kq * 16 + lo) * 8);
            pa[0][0] = mfma16(a0, prep[ki * 2], pa[0][0]);
            pa[0][1] = mfma16(a0, prep[ki * 2 + 1], pa[0][1]);
            pa[1][0] = mfma16(a1, prep[ki * 2], pa[1][0]);
            pa[1][1] = mfma16(a1, prep[ki * 2 + 1], pa[1][1]);
        }
        float pb0 = pb[n0 + lo], pb1 = pb[n0 + 16 + lo];
#pragma unroll
        for (int mt = 0; mt < 2; ++mt)
#pragma unroll
            for (int r = 0; r < 4; ++r) {
                Xl[(mt * 16 + qd * 4 + r) * 132 + n0 + lo] += pa[mt][0][r] + pb0;
                Xl[(mt * 16 + qd * 4 + r) * 132 + n0 + 16 + lo] += pa[mt][1][r] + pb1;
            }
    }
    int n0h = wv * 64;
    short8 pre1[4];                                    // ffn1 h0 ki=0
#pragma unroll
    for (int t = 0; t < 4; ++t)
        pre1[t] = *(const short8*)(w1 + ((size_t)qd * 512 + n0h + t * 16 + lo) * 8);
    __syncthreads();
    ln_tile16(Xl, l2s, l2b, SB, tid, 1e-5f);
    ln_tile16(Xl + 16 * 132, l2s, l2b, SB + 2048, tid, 1e-5f);
    __syncthreads();
    f32x4 facc[2][2] = {};
    // ---- ffn1 h0 ----
    {
        f32x4 fa[2][4] = {};
#pragma unroll
        for (int ki = 0; ki < 4; ++ki) {
            int kq = ki * 4 + qd;
            short8 a0 = *(const short8*)(SB + (kq * 16 + lo) * 8);
            short8 a1 = *(const short8*)(SB + 2048 + (kq * 16 + lo) * 8);
#pragma unroll
            for (int t = 0; t < 4; ++t) {
                short8 bf = (ki == 0) ? pre1[t]
                                      : *(const short8*)(w1 + ((size_t)kq * 512 + n0h + t * 16 + lo) * 8);
                fa[0][t] = mfma16(a0, bf, fa[0][t]);
                fa[1][t] = mfma16(a1, bf, fa[1][t]);
            }
        }
#pragma unroll
        for (int t = 0; t < 4; ++t) {
            int nl = n0h + t * 16 + lo;
            float bvv = b1[nl];
#pragma unroll
            for (int mt = 0; mt < 2; ++mt)
#pragma unroll
                for (int r = 0; r < 4; ++r) {
                    float x = fa[mt][t][r] + bvv;
                    float u = x * (0.7978845608f + 0.0356774081f * x * x);
                    x = x / (1.f + __expf(-2.f * u));
                    Uh[(mt * 32 + (nl >> 3)) * 136 + (qd * 4 + r) * 8 + (nl & 7)] = f2bs(x);
                }
        }
    }
    short8 pre2a = *(const short8*)(w2 + ((size_t)qd * 128 + n0 + lo) * 8);       // ffn2 h0 ki=0
    short8 pre2b = *(const short8*)(w2 + ((size_t)qd * 128 + n0 + 16 + lo) * 8);
    short8 pre1b[4];                                   // ffn1 h1 ki=0
#pragma unroll
    for (int t = 0; t < 4; ++t)
        pre1b[t] = *(const short8*)(w1 + ((size_t)qd * 512 + 256 + n0h + t * 16 + lo) * 8);
    __syncthreads();
    // ---- ffn2 h0 ----
#pragma unroll
    for (int ki = 0; ki < 8; ++ki) {
        int kq2 = ki * 4 + qd;
        short8 a0 = *(const short8*)(Uh + kq2 * 136 + lo * 8);
        short8 a1 = *(const short8*)(Uh + (32 + kq2) * 136 + lo * 8);
        short8 b0 = (ki == 0) ? pre2a : *(const short8*)(w2 + ((size_t)kq2 * 128 + n0 + lo) * 8);
        short8 b1 = (ki == 0) ? pre2b : *(const short8*)(w2 + ((size_t)kq2 * 128 + n0 + 16 + lo) * 8);
        facc[0][0] = mfma16(a0, b0, facc[0][0]);
        facc[0][1] = mfma16(a0, b1, facc[0][1]);
        facc[1][0] = mfma16(a1, b0, facc[1][0]);
        facc[1][1] = mfma16(a1, b1, facc[1][1]);
    }
    short8 pre3a = *(const short8*)(w2 + ((size_t)(32 + qd) * 128 + n0 + lo) * 8); // ffn2 h1 ki=0
    short8 pre3b = *(const short8*)(w2 + ((size_t)(32 + qd) * 128 + n0 + 16 + lo) * 8);
    __syncthreads();
    // ---- ffn1 h1 ----
    {
        f32x4 fa[2][4] = {};
#pragma unroll
        for (int ki = 0; ki < 4; ++ki) {
            int kq = ki * 4 + qd;
            short8 a0 = *(const short8*)(SB + (kq * 16 + lo) * 8);
            short8 a1 = *(const short8*)(SB + 2048 + (kq * 16 + lo) * 8);
#pragma unroll
            for (int t = 0; t < 4; ++t) {
                short8 bf = (ki == 0) ? pre1b[t]
                                      : *(const short8*)(w1 + ((size_t)kq * 512 + 256 + n0h + t * 16 + lo) * 8);
                fa[0][t] = mfma16(a0, bf, fa[0][t]);
                fa[1][t] = mfma16(a1, bf, fa[1][t]);
            }
        }
#pragma unroll
        for (int t = 0; t < 4; ++t) {
            int nl = n0h + t * 16 + lo;
            float bvv = b1[256 + nl];
#pragma unroll
            for (int mt = 0; mt < 2; ++mt)
#pragma unroll
                for (int r = 0; r < 4; ++r) {
                    float x = fa[mt][t][r] + bvv;
                    float u = x * (0.7978845608f + 0.0356774081f * x * x);
                    x = x / (1.f + __expf(-2.f * u));
                    Uh[(mt * 32 + (nl >> 3)) * 136 + (qd * 4 + r) * 8 + (nl & 7)] = f2bs(x);
                }
        }
    }
    __syncthreads();
    // ---- ffn2 h1 ----
#pragma unroll
    for (int ki = 0; ki < 8; ++ki) {
        int kq2 = ki * 4 + qd;
        short8 a0 = *(const short8*)(Uh + kq2 * 136 + lo * 8);
        short8 a1 = *(const short8*)(Uh + (32 + kq2) * 136 + lo * 8);
        short8 b0 = (ki == 0) ? pre3a : *(const short8*)(w2 + ((size_t)(32 + kq2) * 128 + n0 + lo) * 8);
        short8 b1 = (ki == 0) ? pre3b : *(const short8*)(w2 + ((size_t)(32 + kq2) * 128 + n0 + 16 + lo) * 8);
        facc[0][0] = mfma16(a0, b0, facc[0][0]);
        facc[0][1] = mfma16(a0, b1, facc[0][1]);
        facc[1][0] = mfma16(a1, b0, facc[1][0]);
        facc[1][1] = mfma16(a1, b1, facc[1][1]);
    }
    // ---- residual ----
    {
        float b20 = b2[n0 + lo], b21 = b2[n0 + 16 + lo];
#pragma unroll
        for (int mt = 0; mt < 2; ++mt)
#pragma unroll
            for (int r = 0; r < 4; ++r) {
                Xl[(mt * 16 + qd * 4 + r) * 132 + n0 + lo] += facc[mt][0][r] + b20;
                Xl[(mt * 16 + qd * 4 + r) * 132 + n0 + 16 + lo] += facc[mt][1][r] + b21;
            }
    }
    short8 preq[6];
    if (!LAST) {
#pragma unroll
        for (int t = 0; t < 6; ++t)
            preq[t] = *(const short8*)(wq + ((size_t)qd * 384 + wv * 96 + t * 16 + lo) * 8);
    }
    __syncthreads();
    for (int idx = tid; idx < 1024; idx += 256) {
        int tok = idx >> 5, c = idx & 31;
        *(float4*)(X + (size_t)(mg * 32 + tok) * 128 + c * 4) = *(const float4*)(Xl + tok * 132 + c * 4);
    }
    if (LAST) return;
    ln_tile16(Xl, l1s, l1b, SB, tid, 1e-5f);
    ln_tile16(Xl + 16 * 132, l1s, l1b, SB + 2048, tid, 1e-5f);
    __syncthreads();
    qkv_stage32(SB, wq, qb, preq, mg, wv, lo, qd, Qf, Kf, Vt);
}

// Fused attention: block = (b,h,quarter); Q pre-scaled; P stores raw exp, 1/l folded into O.
__global__ __launch_bounds__(256, 4) void attn(const short* __restrict__ Qf, const short* __restrict__ Kf,
                                               const short* __restrict__ Vt, short* __restrict__ Of) {
    __shared__ __align__(16) short Vl[32 * 296];       // 18.9 KB
    __shared__ __align__(16) short Pl[4][544];         // per-wave 32-key P chunk
    int b = blockIdx.x >> 4, h = (blockIdx.x >> 2) & 3, qc = blockIdx.x & 3;
    int tid = threadIdx.x;
    const short* kf = Kf + (size_t)(b * 4 + h) * (4 * NP_ * 8);
    const short* qf = Qf + (size_t)(b * 4 + h) * (4 * NP_ * 8);
    const short* vt = Vt + (size_t)(b * 4 + h) * (32 * NP_);
    for (int idx = tid; idx < 32 * 37; idx += 256) {
        int d = idx / 37, c8 = idx - d * 37;
        short8 v = {};
        if (c8 < 34) v = *(const short8*)(vt + d * NP_ + c8 * 8);
        *(short8*)(Vl + d * 296 + c8 * 8) = v;
    }
    __syncthreads();
    int wv = tid >> 6, lane = tid & 63, lo = lane & 15, qd = lane >> 4;
    short* Pw = Pl[wv];
    for (int it = 0; it < 2; ++it) {
        int qt;
        if (it == 0) qt = qc * 4 + wv;
        else { if ((qc | wv) != 0) break; qt = 16; }   // wave-uniform
        short8 qfr = *(const short8*)(qf + ((size_t)qd * NP_ + qt * 16 + lo) * 8);
        f32x4 sc[17];
#pragma unroll
        for (int kt = 0; kt < 17; ++kt) {
            short8 kfr = *(const short8*)(kf + ((size_t)qd * NP_ + kt * 16 + lo) * 8);
            f32x4 z = {};
            sc[kt] = mfma16(qfr, kfr, z);
        }
        float mx[4] = {-1e30f, -1e30f, -1e30f, -1e30f};
#pragma unroll
        for (int kt = 0; kt < 17; ++kt) {
            bool valid = (kt * 16 + lo) < 257;
#pragma unroll
            for (int r = 0; r < 4; ++r) {
                float v2 = valid ? sc[kt][r] : -1e30f;
                sc[kt][r] = v2;
                mx[r] = fmaxf(mx[r], v2);
            }
        }
#pragma unroll
        for (int r = 0; r < 4; ++r) {
            mx[r] = fmaxf(mx[r], __shfl_xor(mx[r], 1));
            mx[r] = fmaxf(mx[r], __shfl_xor(mx[r], 2));
            mx[r] = fmaxf(mx[r], __shfl_xor(mx[r], 4));
            mx[r] = fmaxf(mx[r], __shfl_xor(mx[r], 8));
        }
        float l[4] = {0.f, 0.f, 0.f, 0.f};
#pragma unroll
        for (int kt = 0; kt < 17; ++kt)
#pragma unroll
            for (int r = 0; r < 4; ++r) {
                float p = __expf(sc[kt][r] - mx[r]);
                sc[kt][r] = p;
                l[r] += p;
            }
#pragma unroll
        for (int r = 0; r < 4; ++r) {
            l[r] += __shfl_xor(l[r], 1);
            l[r] += __shfl_xor(l[r], 2);
            l[r] += __shfl_xor(l[r], 4);
            l[r] += __shfl_xor(l[r], 8);
        }
        float rl[4];
#pragma unroll
        for (int r = 0; r < 4; ++r) rl[r] = 1.f / l[r];
        f32x4 oa[2] = {};
#pragma unroll
        for (int ks = 0; ks < 9; ++ks) {
#pragma unroll
            for (int kt2 = 0; kt2 < 2; ++kt2) {
                int kt = ks * 2 + kt2;
                int lkey = kt2 * 16 + lo;
#pragma unroll
                for (int r = 0; r < 4; ++r) {
                    short pv = (kt < 17) ? f2bs(sc[kt][r]) : (short)0;
                    Pw[(lkey >> 3) * 128 + (qd * 4 + r) * 8 + (lkey & 7)] = pv;
                }
            }
            short8 pf = *(const short8*)(Pw + (qd * 16 + lo) * 8);
#pragma unroll
            for (int nt = 0; nt < 2; ++nt) {
                short8 vfr = *(const short8*)(Vl + (nt * 16 + lo) * 296 + ks * 32 + qd * 8);
                oa[nt] = mfma16(pf, vfr, oa[nt]);
            }
        }
        int tile = b * TPB_ + qt;
#pragma unroll
        for (int nt = 0; nt < 2; ++nt)
#pragma unroll
            for (int r = 0; r < 4; ++r) {
                int qq = qt * 16 + qd * 4 + r;
                if (qq <= 256) {
                    int col = h * 32 + nt * 16 + lo;
                    Of[(size_t)tile * 2048 + (col >> 3) * 128 + (qd * 4 + r) * 8 + (col & 7)] = f2bs(oa[nt][r] * rl[r]);
                }
            }
    }
}

// final LN (token 0 only, eps 1e-6) + fc head
__global__ __launch_bounds__(64) void final_head(const float* __restrict__ X, const float* __restrict__ fs,
                                                 const float* __restrict__ fb, const float* __restrict__ fcw,
                                                 const float* __restrict__ fcb, float* __restrict__ out) {
    int b = blockIdx.x, lane = threadIdx.x;
    float2 v = *(const float2*)(X + (size_t)b * NP_ * 128 + lane * 2);
    float sum = v.x + v.y;
#pragma unroll
    for (int m = 1; m < 64; m <<= 1) sum += __shfl_xor(sum, m);
    float mean = sum * (1.f / 128.f);
    float d0 = v.x - mean, d1 = v.y - mean;
    float vs = d0 * d0 + d1 * d1;
#pragma unroll
    for (int m = 1; m < 64; m <<= 1) vs += __shfl_xor(vs, m);
    float rs = rsqrtf(vs * (1.f / 128.f) + 1e-6f);
    int e = lane * 2;
    float f0 = d0 * rs * fs[e] + fb[e];
    float f1 = d1 * rs * fs[e + 1] + fb[e + 1];
    out[128 + b * 128 + e] = f0;
    out[128 + b * 128 + e + 1] = f1;
    float p0 = f0 * fcw[e] + f1 * fcw[e + 1];
    float p1 = f0 * fcw[128 + e] + f1 * fcw[128 + e + 1];
#pragma unroll
    for (int m = 1; m < 64; m <<= 1) {
        p0 += __shfl_xor(p0, m);
        p1 += __shfl_xor(p1, m);
    }
    if (lane == 0) {
        out[b * 2 + 0] = p0 + fcb[0];
        out[b * 2 + 1] = p1 + fcb[1];
    }
}

extern "C" void kernel_launch(void* const* d_in, const int* in_sizes, int n_in,
                              void* d_out, int out_size, void* d_ws, size_t ws_size,
                              hipStream_t stream) {
    const float* feat    = (const float*)d_in[0];
    const float* conv_w  = (const float*)d_in[1];
    const float* conv_b  = (const float*)d_in[2];
    const float* pos_emb = (const float*)d_in[3];
    const float* cls_tok = (const float*)d_in[4];
    const float* ln1_s   = (const float*)d_in[5];
    const float* ln1_b   = (const float*)d_in[6];
    const float* qkv_w   = (const float*)d_in[7];
    const float* qkv_b   = (const float*)d_in[8];
    const float* proj_w  = (const float*)d_in[9];
    const float* proj_b  = (const float*)d_in[10];
    const float* ln2_s   = (const float*)d_in[11];
    const float* ln2_b   = (const float*)d_in[12];
    const float* ffn1_w  = (const float*)d_in[13];
    const float* ffn1_b  = (const float*)d_in[14];
    const float* ffn2_w  = (const float*)d_in[15];
    const float* ffn2_b  = (const float*)d_in[16];
    const float* fn_s    = (const float*)d_in[17];
    const float* fn_b    = (const float*)d_in[18];
    const float* fc_w    = (const float*)d_in[19];
    const float* fc_b    = (const float*)d_in[20];

    char* p = (char*)d_ws;
    auto alloc = [&](size_t bytes) { char* r = p; p += (bytes + 255) & ~(size_t)255; return r; };
    short* wq  = (short*)alloc((size_t)589824 * 2);
    short* wp  = (short*)alloc((size_t)196608 * 2);
    short* w1  = (short*)alloc((size_t)786432 * 2);
    short* w2  = (short*)alloc((size_t)786432 * 2);
    short* wc  = (short*)alloc((size_t)294912 * 2);
    float* X   = (float*)alloc((size_t)MP_ * 128 * 4);
    short* Qf  = (short*)alloc((size_t)64 * 16 * NP_ * 8 * 2);
    short* Kf  = (short*)alloc((size_t)64 * 16 * NP_ * 8 * 2);
    short* Vt  = (short*)alloc((size_t)64 * 4 * 32 * NP_ * 2);
    short* Of  = (short*)alloc((size_t)(MP_ / 16) * 2048 * 2);

    repack_all<<<2304, 256, 0, stream>>>(qkv_w, proj_w, ffn1_w, ffn2_w, conv_w, wq, wp, w1, w2, wc);
    conv_gemm<<<512, 256, 0, stream>>>(feat, wc, conv_b, pos_emb, cls_tok, X);

    qkv0<<<544, 256, 0, stream>>>(X, wq, qkv_b, ln1_s, ln1_b, Qf, Kf, Vt);
    for (int l = 0; l < 12; ++l) {
        attn<<<1024, 256, 0, stream>>>(Qf, Kf, Vt, Of);
        if (l < 11)
            layer_tail<0><<<544, 256, 0, stream>>>(Of, wp + (size_t)l * 16384, proj_b + l * 128,
                                                   ln2_s + l * 128, ln2_b + l * 128,
                                                   w1 + (size_t)l * 65536, ffn1_b + l * 512,
                                                   w2 + (size_t)l * 65536, ffn2_b + l * 128, X,
                                                   ln1_s + (l + 1) * 128, ln1_b + (l + 1) * 128,
                                                   wq + (size_t)(l + 1) * 49152, qkv_b + (l + 1) * 384,
                                                   Qf, Kf, Vt);
        else
            layer_tail<1><<<544, 256, 0, stream>>>(Of, wp + (size_t)l * 16384, proj_b + l * 128,
                                                   ln2_s + l * 128, ln2_b + l * 128,
                                                   w1 + (size_t)l * 65536, ffn1_b + l * 512,
                                                   w2 + (size_t)l * 65536, ffn2_b + l * 128, X,
                                                   ln1_s, ln1_b, wq, qkv_b, Qf, Kf, Vt);
    }
    final_head<<<64, 64, 0, stream>>>(X, fn_s, fn_b, fc_w, fc_b, (float*)d_out);
}